// Round 1
// baseline (1757.515 us; speedup 1.0000x reference)
//
#include <hip/hip_runtime.h>
#include <math.h>

#define NHD 8
#define HD 32
#define NREF 30
#define RB 4
#define NWIN 144
#define NTOK 64
#define IMG_H (NWIN*NTOK)        /* 9216  */
#define LN_CNT (IMG_H*NREF)      /* 276480 */
#define SCALE 0.1767766952966369f
#define LN_EPS 1e-5f

__device__ __forceinline__ float gelu_f(float v) {
    return 0.5f * v * (1.0f + erff(v * 0.7071067811865476f));
}

// ---------------- ref_q / ref_v prep (tiny) ----------------
__global__ __launch_bounds__(256) void k_refprep(
    const float* __restrict__ x_ref, const float* __restrict__ rw,
    const float* __restrict__ rbias, const float* __restrict__ dmu,
    const float* __restrict__ dls, float* __restrict__ ref_q,
    float* __restrict__ ref_v) {
    __shared__ float Wl[60][NREF];
    __shared__ float Bl[60];
    const int rb = blockIdx.x;
    const int t = threadIdx.x;
    for (int i = t; i < 60 * NREF; i += 256) Wl[i / NREF][i % NREF] = rw[i];
    if (t < 60) Bl[t] = rbias[t];
    __syncthreads();
    const int d = t;                       // 0..255
    float xr[NREF];
#pragma unroll
    for (int r = 0; r < NREF; ++r) xr[r] = x_ref[(rb * 256 + d) * NREF + r];
    const int h = d >> 5, hd = d & 31;
    const float mu = dmu[d], sg = expf(dls[d]);
    for (int j = 0; j < 60; ++j) {
        float acc = Bl[j];
#pragma unroll
        for (int r = 0; r < NREF; ++r) acc += xr[r] * Wl[j][r];
        if (j < NREF)
            ref_q[((rb * NHD + h) * NREF + j) * HD + hd] = mu + sg * acc;
        else
            ref_v[((rb * NHD + h) * NREF + (j - NREF)) * HD + hd] = acc;
    }
}

// ---------------- qkv GEMM: (36864x256)@(256x768)^T + scatter ----------------
__global__ __launch_bounds__(256) void k_qkv(
    const float* __restrict__ x, const float* __restrict__ w,
    const float* __restrict__ bias, float* __restrict__ qb,
    float* __restrict__ kb, float* __restrict__ vb) {
    __shared__ __align__(16) float As[32][68];
    __shared__ __align__(16) float Bs[32][68];
    const int t = threadIdx.x;
    const int r0 = blockIdx.x * 64;
    const int c0 = blockIdx.y * 64;
    const int tx = t & 15, ty = t >> 4;
    float acc[4][4] = {{0.f}};
    for (int k0 = 0; k0 < 256; k0 += 32) {
        __syncthreads();
        int u = t;
#pragma unroll
        for (int rep = 0; rep < 2; ++rep) {
            const int row = u >> 3, c4 = u & 7;
            float4 av = *reinterpret_cast<const float4*>(&x[(size_t)(r0 + row) * 256 + k0 + c4 * 4]);
            As[c4 * 4 + 0][row] = av.x; As[c4 * 4 + 1][row] = av.y;
            As[c4 * 4 + 2][row] = av.z; As[c4 * 4 + 3][row] = av.w;
            float4 bv = *reinterpret_cast<const float4*>(&w[(size_t)(c0 + row) * 256 + k0 + c4 * 4]);
            Bs[c4 * 4 + 0][row] = bv.x; Bs[c4 * 4 + 1][row] = bv.y;
            Bs[c4 * 4 + 2][row] = bv.z; Bs[c4 * 4 + 3][row] = bv.w;
            u += 256;
        }
        __syncthreads();
#pragma unroll
        for (int kk = 0; kk < 32; ++kk) {
            float a[4], b[4];
            *reinterpret_cast<float4*>(a) = *reinterpret_cast<const float4*>(&As[kk][ty * 4]);
            *reinterpret_cast<float4*>(b) = *reinterpret_cast<const float4*>(&Bs[kk][tx * 4]);
#pragma unroll
            for (int i = 0; i < 4; ++i)
#pragma unroll
                for (int j = 0; j < 4; ++j) acc[i][j] += a[i] * b[j];
        }
    }
#pragma unroll
    for (int i = 0; i < 4; ++i) {
        const int row = r0 + ty * 4 + i;
        const int bb = row >> 6, n = row & 63;
#pragma unroll
        for (int j = 0; j < 4; ++j) {
            const int col = c0 + tx * 4 + j;
            const float val = acc[i][j] + bias[col];
            const int i3 = col >> 8, rem = col & 255;
            const int h = rem >> 5, hd = rem & 31;
            float* dst = (i3 == 0) ? qb : (i3 == 1) ? kb : vb;
            dst[(size_t)((bb * NHD + h) * NTOK + n) * HD + hd] = val;
        }
    }
}

// ---------------- proj GEMM: (36864x256)@(256x256)^T ----------------
__global__ __launch_bounds__(256) void k_proj(
    const float* __restrict__ A, const float* __restrict__ w,
    const float* __restrict__ bias, float* __restrict__ out) {
    __shared__ __align__(16) float As[32][68];
    __shared__ __align__(16) float Bs[32][68];
    const int t = threadIdx.x;
    const int r0 = blockIdx.x * 64;
    const int c0 = blockIdx.y * 64;
    const int tx = t & 15, ty = t >> 4;
    float acc[4][4] = {{0.f}};
    for (int k0 = 0; k0 < 256; k0 += 32) {
        __syncthreads();
        int u = t;
#pragma unroll
        for (int rep = 0; rep < 2; ++rep) {
            const int row = u >> 3, c4 = u & 7;
            float4 av = *reinterpret_cast<const float4*>(&A[(size_t)(r0 + row) * 256 + k0 + c4 * 4]);
            As[c4 * 4 + 0][row] = av.x; As[c4 * 4 + 1][row] = av.y;
            As[c4 * 4 + 2][row] = av.z; As[c4 * 4 + 3][row] = av.w;
            float4 bv = *reinterpret_cast<const float4*>(&w[(size_t)(c0 + row) * 256 + k0 + c4 * 4]);
            Bs[c4 * 4 + 0][row] = bv.x; Bs[c4 * 4 + 1][row] = bv.y;
            Bs[c4 * 4 + 2][row] = bv.z; Bs[c4 * 4 + 3][row] = bv.w;
            u += 256;
        }
        __syncthreads();
#pragma unroll
        for (int kk = 0; kk < 32; ++kk) {
            float a[4], b[4];
            *reinterpret_cast<float4*>(a) = *reinterpret_cast<const float4*>(&As[kk][ty * 4]);
            *reinterpret_cast<float4*>(b) = *reinterpret_cast<const float4*>(&Bs[kk][tx * 4]);
#pragma unroll
            for (int i = 0; i < 4; ++i)
#pragma unroll
                for (int j = 0; j < 4; ++j) acc[i][j] += a[i] * b[j];
        }
    }
#pragma unroll
    for (int i = 0; i < 4; ++i) {
        const int row = r0 + ty * 4 + i;
#pragma unroll
        for (int j = 0; j < 4; ++j) {
            const int col = c0 + tx * 4 + j;
            out[(size_t)row * 256 + col] = acc[i][j] + bias[col];
        }
    }
}

// ---------------- ref scores: q . ref_q -> (rb,h, y=w*64+n, r) ----------------
__global__ __launch_bounds__(64) void k_scores(
    const float* __restrict__ qbuf, const float* __restrict__ ref_q,
    float* __restrict__ scores) {
    const int bid = blockIdx.x;            // ((rb*8+h)*144 + w)
    const int w = bid % NWIN;
    const int rh = bid / NWIN;
    const int h = rh % NHD, rb = rh / NHD;
    __shared__ __align__(16) float qs[64][36];
    __shared__ __align__(16) float rs[NREF][32];
    __shared__ float outb[64 * NREF];
    const int t = threadIdx.x;
    const float* qsrc = &qbuf[(size_t)((rb * NWIN + w) * NHD + h) * NTOK * HD];
    for (int u = t; u < 512; u += 64) {
        const int row = u >> 3, c4 = u & 7;
        *reinterpret_cast<float4*>(&qs[row][c4 * 4]) =
            *reinterpret_cast<const float4*>(&qsrc[u * 4]);
    }
    const float* rsrc = &ref_q[(size_t)(rb * NHD + h) * NREF * HD];
    for (int u = t; u < NREF * 8; u += 64) {
        const int row = u >> 3, c4 = u & 7;
        *reinterpret_cast<float4*>(&rs[row][c4 * 4]) =
            *reinterpret_cast<const float4*>(&rsrc[u * 4]);
    }
    __syncthreads();
    const int n = t;
    float q[32];
#pragma unroll
    for (int c4 = 0; c4 < 8; ++c4)
        *reinterpret_cast<float4*>(&q[c4 * 4]) = *reinterpret_cast<const float4*>(&qs[n][c4 * 4]);
    for (int r = 0; r < NREF; ++r) {
        float acc = 0.f;
#pragma unroll
        for (int d = 0; d < 32; ++d) acc += q[d] * rs[r][d];
        outb[n * NREF + r] = acc;
    }
    __syncthreads();
    float* dst = &scores[(size_t)((rb * NHD + h) * IMG_H + w * 64) * NREF];
    for (int u = t; u < 64 * NREF; u += 64) dst[u] = outb[u];
}

// ---------------- conv 3x3 (NCHW 4,8,9216,30) + sum/sumsq stats ----------------
__global__ __launch_bounds__(256) void k_conv(
    const float* __restrict__ scores, const float* __restrict__ conv_w,
    const float* __restrict__ conv_b, float* __restrict__ upd,
    float* __restrict__ stats) {
    const int bid = blockIdx.x;            // rb*288 + ychunk
    const int rb = bid / 288;
    const int y0 = (bid % 288) * 32;
    __shared__ float li[8][34][30];
    __shared__ __align__(16) float wl[72][8];
    __shared__ float red[4][8][2];
    const int t = threadIdx.x;
    for (int f = t; f < 8 * 34 * 30; f += 256) {
        const int ci = f / (34 * 30);
        const int rem = f % (34 * 30);
        const int yy = rem / 30, xx = rem % 30;
        const int y = y0 - 1 + yy;
        float val = 0.f;
        if (y >= 0 && y < IMG_H)
            val = scores[(size_t)((rb * NHD + ci) * IMG_H + y) * NREF + xx];
        li[ci][yy][xx] = val;
    }
    for (int f = t; f < 576; f += 256) {
        const int co = f / 72, r = f % 72;
        wl[r][co] = conv_w[f];             // conv_w[co*72 + r]
    }
    __syncthreads();
    float cb[8];
#pragma unroll
    for (int co = 0; co < 8; ++co) cb[co] = conv_b[co];
    float ls[8] = {0.f}, lss[8] = {0.f};
    for (int s = t; s < 32 * 30; s += 256) {
        const int yl = s / 30, xx = s % 30;
        float acc[8];
#pragma unroll
        for (int co = 0; co < 8; ++co) acc[co] = cb[co];
#pragma unroll
        for (int ci = 0; ci < 8; ++ci)
#pragma unroll
            for (int dy = 0; dy < 3; ++dy)
#pragma unroll
                for (int dx = 0; dx < 3; ++dx) {
                    const int xg = xx + dx - 1;
                    const float a = (xg >= 0 && xg < 30) ? li[ci][yl + dy][xg] : 0.f;
                    const int r = ci * 9 + dy * 3 + dx;
                    float4 w0 = *reinterpret_cast<const float4*>(&wl[r][0]);
                    float4 w1 = *reinterpret_cast<const float4*>(&wl[r][4]);
                    acc[0] += a * w0.x; acc[1] += a * w0.y;
                    acc[2] += a * w0.z; acc[3] += a * w0.w;
                    acc[4] += a * w1.x; acc[5] += a * w1.y;
                    acc[6] += a * w1.z; acc[7] += a * w1.w;
                }
        const int y = y0 + yl;
#pragma unroll
        for (int co = 0; co < 8; ++co) {
            upd[(size_t)((rb * NHD + co) * IMG_H + y) * NREF + xx] = acc[co];
            ls[co] += acc[co];
            lss[co] += acc[co] * acc[co];
        }
    }
#pragma unroll
    for (int co = 0; co < 8; ++co) {
        float a = ls[co], b = lss[co];
        for (int off = 32; off; off >>= 1) {
            a += __shfl_down(a, off);
            b += __shfl_down(b, off);
        }
        if ((t & 63) == 0) { red[t >> 6][co][0] = a; red[t >> 6][co][1] = b; }
    }
    __syncthreads();
    if (t < 8) {
        const float a = red[0][t][0] + red[1][t][0] + red[2][t][0] + red[3][t][0];
        const float b = red[0][t][1] + red[1][t][1] + red[2][t][1] + red[3][t][1];
        atomicAdd(&stats[(rb * NHD + t) * 2], a);
        atomicAdd(&stats[(rb * NHD + t) * 2 + 1], b);
    }
}

// ---------------- LN + gelu + residual ----------------
__global__ __launch_bounds__(256) void k_apply(
    const float* __restrict__ upd, float* __restrict__ scores,
    const float* __restrict__ stats) {
    const int bid = blockIdx.x;            // 32*270
    const int img = bid / 270;
    const int off = (bid % 270) * 1024;
    const float s0 = stats[img * 2], s1 = stats[img * 2 + 1];
    const float mean = s0 * (1.f / LN_CNT);
    const float var = s1 * (1.f / LN_CNT) - mean * mean;
    const float rsig = rsqrtf(var + LN_EPS);
    const size_t base = (size_t)img * LN_CNT + off + threadIdx.x * 4;
    float4 u = *reinterpret_cast<const float4*>(&upd[base]);
    float4 sc = *reinterpret_cast<const float4*>(&scores[base]);
    sc.x += gelu_f((u.x - mean) * rsig);
    sc.y += gelu_f((u.y - mean) * rsig);
    sc.z += gelu_f((u.z - mean) * rsig);
    sc.w += gelu_f((u.w - mean) * rsig);
    *reinterpret_cast<float4*>(&scores[base]) = sc;
}

// ---------------- softmax over NREF + @ref_v * SCALE -> q_new ----------------
__global__ __launch_bounds__(64) void k_qnew(
    const float* __restrict__ scores, const float* __restrict__ ref_v,
    float* __restrict__ qbuf) {
    const int bid = blockIdx.x;            // ((rb*8+h)*144 + w)
    const int w = bid % NWIN;
    const int rh = bid / NWIN;
    const int h = rh % NHD, rb = rh / NHD;
    __shared__ float sl[64][NREF];
    __shared__ __align__(16) float rv[NREF][32];
    __shared__ __align__(16) float ob[64][32];
    const int t = threadIdx.x;
    const float* src = &scores[(size_t)((rb * NHD + h) * IMG_H + w * 64) * NREF];
    for (int u = t; u < 64 * NREF; u += 64) sl[u / NREF][u % NREF] = src[u];
    const float* rvs = &ref_v[(size_t)(rb * NHD + h) * NREF * HD];
    for (int u = t; u < NREF * 8; u += 64) {
        const int r = u >> 3, c4 = u & 7;
        *reinterpret_cast<float4*>(&rv[r][c4 * 4]) =
            *reinterpret_cast<const float4*>(&rvs[u * 4]);
    }
    __syncthreads();
    const int n = t;
    float p[NREF];
    float mx = -1e30f;
#pragma unroll
    for (int r = 0; r < NREF; ++r) { p[r] = sl[n][r]; mx = fmaxf(mx, p[r]); }
    float sum = 0.f;
#pragma unroll
    for (int r = 0; r < NREF; ++r) { p[r] = expf(p[r] - mx); sum += p[r]; }
    const float inv = SCALE / sum;
    float acc[32] = {0.f};
#pragma unroll
    for (int r = 0; r < NREF; ++r) {
        const float pr = p[r] * inv;
#pragma unroll
        for (int d = 0; d < 32; ++d) acc[d] += pr * rv[r][d];
    }
#pragma unroll
    for (int d = 0; d < 32; ++d) ob[n][d] = acc[d];
    __syncthreads();
    float* dst = &qbuf[(size_t)((rb * NWIN + w) * NHD + h) * NTOK * HD];
    for (int u = t; u < 512; u += 64)
        *reinterpret_cast<float4*>(&dst[u * 4]) =
            *reinterpret_cast<const float4*>(&ob[0][0] + u * 4);
}

// ---------------- window attention per (b,h) ----------------
__global__ __launch_bounds__(256) void k_wattn(
    const float* __restrict__ qbuf, const float* __restrict__ kbuf,
    const float* __restrict__ vbuf, const float* __restrict__ bias_table,
    const int* __restrict__ rel_index, const float* __restrict__ mask,
    float* __restrict__ pre) {
    const int bid = blockIdx.x;            // b*8 + h
    const int h = bid & 7;
    const int b = bid >> 3;
    const int w = b % NWIN;
    __shared__ __align__(16) float qs[64][36];
    __shared__ __align__(16) float ks[64][36];
    __shared__ __align__(16) float vs[64][36];
    __shared__ float S[64][66];
    const int t = threadIdx.x;
    const float* qsrc = &qbuf[(size_t)bid * 2048];
    const float* ksrc = &kbuf[(size_t)bid * 2048];
    const float* vsrc = &vbuf[(size_t)bid * 2048];
    for (int u = t; u < 512; u += 256) {
        const int row = u >> 3, c4 = u & 7;
        *reinterpret_cast<float4*>(&qs[row][c4 * 4]) = *reinterpret_cast<const float4*>(&qsrc[u * 4]);
        *reinterpret_cast<float4*>(&ks[row][c4 * 4]) = *reinterpret_cast<const float4*>(&ksrc[u * 4]);
        *reinterpret_cast<float4*>(&vs[row][c4 * 4]) = *reinterpret_cast<const float4*>(&vsrc[u * 4]);
    }
    __syncthreads();
    const int n = t >> 2, quad = t & 3;
    float q[32];
#pragma unroll
    for (int c4 = 0; c4 < 8; ++c4)
        *reinterpret_cast<float4*>(&q[c4 * 4]) = *reinterpret_cast<const float4*>(&qs[n][c4 * 4]);
    const int* ri = &rel_index[n * 64];
    const float* mrow = &mask[(size_t)(w * 64 + n) * 64];
    for (int mm = 0; mm < 16; ++mm) {
        const int m = quad * 16 + mm;
        float acc = 0.f;
#pragma unroll
        for (int d = 0; d < 32; ++d) acc += q[d] * ks[m][d];
        acc += bias_table[ri[m] * NHD + h] + mrow[m];
        S[n][m] = acc;
    }
    __syncthreads();
    float mx = -1e30f;
    for (int mm = 0; mm < 16; ++mm) mx = fmaxf(mx, S[n][quad * 16 + mm]);
    mx = fmaxf(mx, __shfl_xor(mx, 1));
    mx = fmaxf(mx, __shfl_xor(mx, 2));
    float sum = 0.f;
    for (int mm = 0; mm < 16; ++mm) {
        const float p = expf(S[n][quad * 16 + mm] - mx);
        S[n][quad * 16 + mm] = p;
        sum += p;
    }
    sum += __shfl_xor(sum, 1);
    sum += __shfl_xor(sum, 2);
    const float inv = 1.f / sum;
    __syncthreads();
    float acc[8] = {0.f};
    for (int m = 0; m < 64; ++m) {
        const float p = S[n][m];
#pragma unroll
        for (int d = 0; d < 8; ++d) acc[d] += p * vs[m][quad * 8 + d];
    }
    float* dst = &pre[(size_t)(b * 64 + n) * 256 + h * 32 + quad * 8];
#pragma unroll
    for (int d = 0; d < 8; ++d) dst[d] = acc[d] * inv;
}

extern "C" void kernel_launch(void* const* d_in, const int* in_sizes, int n_in,
                              void* d_out, int out_size, void* d_ws, size_t ws_size,
                              hipStream_t stream) {
    const float* x          = (const float*)d_in[0];
    const float* mask       = (const float*)d_in[1];
    const float* x_ref      = (const float*)d_in[2];
    const float* qkv_w      = (const float*)d_in[3];
    const float* qkv_b      = (const float*)d_in[4];
    const float* proj_w     = (const float*)d_in[5];
    const float* proj_b     = (const float*)d_in[6];
    const float* bias_table = (const float*)d_in[7];
    const float* diff_mu    = (const float*)d_in[8];
    const float* diff_ls    = (const float*)d_in[9];
    const float* ref_qk_w   = (const float*)d_in[10];
    const float* ref_qk_b   = (const float*)d_in[11];
    const float* conv_w     = (const float*)d_in[12];
    const float* conv_b     = (const float*)d_in[13];
    const int*   rel_index  = (const int*)d_in[14];
    float* out = (float*)d_out;
    float* ws = (float*)d_ws;

    float* qb  = ws;                       // 9437184
    float* kb  = qb + 9437184;             // 9437184
    float* vb  = kb + 9437184;             // 9437184
    float* sc  = vb + 9437184;             // 8847360
    float* up  = sc + 8847360;             // 8847360
    float* pre = sc;                       // alias: sc/up dead after k_qnew
    float* rq  = up + 8847360;             // 30720
    float* rv  = rq + 30720;               // 30720
    float* st  = rv + 30720;               // 64

    k_refprep<<<RB, 256, 0, stream>>>(x_ref, ref_qk_w, ref_qk_b, diff_mu, diff_ls, rq, rv);
    dim3 g1(576, 12);
    k_qkv<<<g1, 256, 0, stream>>>(x, qkv_w, qkv_b, qb, kb, vb);
    k_scores<<<RB * NHD * NWIN, 64, 0, stream>>>(qb, rq, sc);
    for (int it = 0; it < 3; ++it) {
        hipMemsetAsync(st, 0, 64 * sizeof(float), stream);
        k_conv<<<RB * 288, 256, 0, stream>>>(sc, conv_w, conv_b, up, st);
        k_apply<<<32 * 270, 256, 0, stream>>>(up, sc, st);
    }
    k_qnew<<<RB * NHD * NWIN, 64, 0, stream>>>(sc, rv, qb);
    k_wattn<<<576 * NHD, 256, 0, stream>>>(qb, kb, vb, bias_table, rel_index, mask, pre);
    dim3 g2(576, 4);
    k_proj<<<g2, 256, 0, stream>>>(pre, proj_w, proj_b, out);
}

// Round 2
// 990.369 us; speedup vs baseline: 1.7746x; 1.7746x over previous
//
#include <hip/hip_runtime.h>
#include <math.h>

#define NHD 8
#define HD 32
#define NREF 30
#define RB 4
#define NWIN 144
#define NTOK 64
#define IMG_H (NWIN*NTOK)        /* 9216  */
#define LN_CNT (IMG_H*NREF)      /* 276480 */
#define SCALE 0.1767766952966369f
#define LN_EPS 1e-5f

__device__ __forceinline__ float gelu_f(float v) {
    return 0.5f * v * (1.0f + erff(v * 0.7071067811865476f));
}

// ---------------- ref_q / ref_v prep (tiny) ----------------
__global__ __launch_bounds__(256) void k_refprep(
    const float* __restrict__ x_ref, const float* __restrict__ rw,
    const float* __restrict__ rbias, const float* __restrict__ dmu,
    const float* __restrict__ dls, float* __restrict__ ref_q,
    float* __restrict__ ref_v) {
    __shared__ float Wl[60][NREF];
    __shared__ float Bl[60];
    const int rb = blockIdx.x;
    const int t = threadIdx.x;
    for (int i = t; i < 60 * NREF; i += 256) Wl[i / NREF][i % NREF] = rw[i];
    if (t < 60) Bl[t] = rbias[t];
    __syncthreads();
    const int d = t;                       // 0..255
    float xr[NREF];
#pragma unroll
    for (int r = 0; r < NREF; ++r) xr[r] = x_ref[(rb * 256 + d) * NREF + r];
    const int h = d >> 5, hd = d & 31;
    const float mu = dmu[d], sg = expf(dls[d]);
    for (int j = 0; j < 60; ++j) {
        float acc = Bl[j];
#pragma unroll
        for (int r = 0; r < NREF; ++r) acc += xr[r] * Wl[j][r];
        if (j < NREF)
            ref_q[((rb * NHD + h) * NREF + j) * HD + hd] = mu + sg * acc;
        else
            ref_v[((rb * NHD + h) * NREF + (j - NREF)) * HD + hd] = acc;
    }
}

// ---------------- qkv GEMM: (36864x256)@(256x768)^T + scatter ----------------
__global__ __launch_bounds__(256) void k_qkv(
    const float* __restrict__ x, const float* __restrict__ w,
    const float* __restrict__ bias, float* __restrict__ qb,
    float* __restrict__ kb, float* __restrict__ vb) {
    __shared__ __align__(16) float As[32][68];
    __shared__ __align__(16) float Bs[32][68];
    const int t = threadIdx.x;
    const int r0 = blockIdx.x * 64;
    const int c0 = blockIdx.y * 64;
    const int tx = t & 15, ty = t >> 4;
    float acc[4][4] = {{0.f}};
    for (int k0 = 0; k0 < 256; k0 += 32) {
        __syncthreads();
        int u = t;
#pragma unroll
        for (int rep = 0; rep < 2; ++rep) {
            const int row = u >> 3, c4 = u & 7;
            float4 av = *reinterpret_cast<const float4*>(&x[(size_t)(r0 + row) * 256 + k0 + c4 * 4]);
            As[c4 * 4 + 0][row] = av.x; As[c4 * 4 + 1][row] = av.y;
            As[c4 * 4 + 2][row] = av.z; As[c4 * 4 + 3][row] = av.w;
            float4 bv = *reinterpret_cast<const float4*>(&w[(size_t)(c0 + row) * 256 + k0 + c4 * 4]);
            Bs[c4 * 4 + 0][row] = bv.x; Bs[c4 * 4 + 1][row] = bv.y;
            Bs[c4 * 4 + 2][row] = bv.z; Bs[c4 * 4 + 3][row] = bv.w;
            u += 256;
        }
        __syncthreads();
#pragma unroll
        for (int kk = 0; kk < 32; ++kk) {
            float a[4], b[4];
            *reinterpret_cast<float4*>(a) = *reinterpret_cast<const float4*>(&As[kk][ty * 4]);
            *reinterpret_cast<float4*>(b) = *reinterpret_cast<const float4*>(&Bs[kk][tx * 4]);
#pragma unroll
            for (int i = 0; i < 4; ++i)
#pragma unroll
                for (int j = 0; j < 4; ++j) acc[i][j] += a[i] * b[j];
        }
    }
#pragma unroll
    for (int i = 0; i < 4; ++i) {
        const int row = r0 + ty * 4 + i;
        const int bb = row >> 6, n = row & 63;
#pragma unroll
        for (int j = 0; j < 4; ++j) {
            const int col = c0 + tx * 4 + j;
            const float val = acc[i][j] + bias[col];
            const int i3 = col >> 8, rem = col & 255;
            const int h = rem >> 5, hd = rem & 31;
            float* dst = (i3 == 0) ? qb : (i3 == 1) ? kb : vb;
            dst[(size_t)((bb * NHD + h) * NTOK + n) * HD + hd] = val;
        }
    }
}

// ---------------- proj GEMM: (36864x256)@(256x256)^T ----------------
__global__ __launch_bounds__(256) void k_proj(
    const float* __restrict__ A, const float* __restrict__ w,
    const float* __restrict__ bias, float* __restrict__ out) {
    __shared__ __align__(16) float As[32][68];
    __shared__ __align__(16) float Bs[32][68];
    const int t = threadIdx.x;
    const int r0 = blockIdx.x * 64;
    const int c0 = blockIdx.y * 64;
    const int tx = t & 15, ty = t >> 4;
    float acc[4][4] = {{0.f}};
    for (int k0 = 0; k0 < 256; k0 += 32) {
        __syncthreads();
        int u = t;
#pragma unroll
        for (int rep = 0; rep < 2; ++rep) {
            const int row = u >> 3, c4 = u & 7;
            float4 av = *reinterpret_cast<const float4*>(&A[(size_t)(r0 + row) * 256 + k0 + c4 * 4]);
            As[c4 * 4 + 0][row] = av.x; As[c4 * 4 + 1][row] = av.y;
            As[c4 * 4 + 2][row] = av.z; As[c4 * 4 + 3][row] = av.w;
            float4 bv = *reinterpret_cast<const float4*>(&w[(size_t)(c0 + row) * 256 + k0 + c4 * 4]);
            Bs[c4 * 4 + 0][row] = bv.x; Bs[c4 * 4 + 1][row] = bv.y;
            Bs[c4 * 4 + 2][row] = bv.z; Bs[c4 * 4 + 3][row] = bv.w;
            u += 256;
        }
        __syncthreads();
#pragma unroll
        for (int kk = 0; kk < 32; ++kk) {
            float a[4], b[4];
            *reinterpret_cast<float4*>(a) = *reinterpret_cast<const float4*>(&As[kk][ty * 4]);
            *reinterpret_cast<float4*>(b) = *reinterpret_cast<const float4*>(&Bs[kk][tx * 4]);
#pragma unroll
            for (int i = 0; i < 4; ++i)
#pragma unroll
                for (int j = 0; j < 4; ++j) acc[i][j] += a[i] * b[j];
        }
    }
#pragma unroll
    for (int i = 0; i < 4; ++i) {
        const int row = r0 + ty * 4 + i;
#pragma unroll
        for (int j = 0; j < 4; ++j) {
            const int col = c0 + tx * 4 + j;
            out[(size_t)row * 256 + col] = acc[i][j] + bias[col];
        }
    }
}

// ---------------- ref scores: q . ref_q -> (rb,h, y=w*64+n, r) ----------------
__global__ __launch_bounds__(64) void k_scores(
    const float* __restrict__ qbuf, const float* __restrict__ ref_q,
    float* __restrict__ scores) {
    const int bid = blockIdx.x;            // ((rb*8+h)*144 + w)
    const int w = bid % NWIN;
    const int rh = bid / NWIN;
    const int h = rh % NHD, rb = rh / NHD;
    __shared__ __align__(16) float qs[64][36];
    __shared__ __align__(16) float rs[NREF][32];
    __shared__ float outb[64 * NREF];
    const int t = threadIdx.x;
    const float* qsrc = &qbuf[(size_t)((rb * NWIN + w) * NHD + h) * NTOK * HD];
    for (int u = t; u < 512; u += 64) {
        const int row = u >> 3, c4 = u & 7;
        *reinterpret_cast<float4*>(&qs[row][c4 * 4]) =
            *reinterpret_cast<const float4*>(&qsrc[u * 4]);
    }
    const float* rsrc = &ref_q[(size_t)(rb * NHD + h) * NREF * HD];
    for (int u = t; u < NREF * 8; u += 64) {
        const int row = u >> 3, c4 = u & 7;
        *reinterpret_cast<float4*>(&rs[row][c4 * 4]) =
            *reinterpret_cast<const float4*>(&rsrc[u * 4]);
    }
    __syncthreads();
    const int n = t;
    float q[32];
#pragma unroll
    for (int c4 = 0; c4 < 8; ++c4)
        *reinterpret_cast<float4*>(&q[c4 * 4]) = *reinterpret_cast<const float4*>(&qs[n][c4 * 4]);
    for (int r = 0; r < NREF; ++r) {
        float acc = 0.f;
#pragma unroll
        for (int d = 0; d < 32; ++d) acc += q[d] * rs[r][d];
        outb[n * NREF + r] = acc;
    }
    __syncthreads();
    float* dst = &scores[(size_t)((rb * NHD + h) * IMG_H + w * 64) * NREF];
    for (int u = t; u < 64 * NREF; u += 64) dst[u] = outb[u];
}

// ---------------- conv 3x3 (NCHW 4,8,9216,30) + sum/sumsq stats ----------------
// x-padded LDS tile (cols 0 and 31 are zero) -> no boundary branch in the
// inner loop; ci-loop NOT unrolled -> VGPR pressure stays low (was 256 + spills).
__global__ __launch_bounds__(256) void k_conv(
    const float* __restrict__ scores, const float* __restrict__ conv_w,
    const float* __restrict__ conv_b, float* __restrict__ upd,
    float* __restrict__ stats) {
    const int bid = blockIdx.x;            // rb*288 + ychunk
    const int rb = bid / 288;
    const int y0 = (bid % 288) * 32;
    __shared__ float li[8][34][32];        // [ci][yy][x+1], x-padded
    __shared__ float wl[72][8];            // [ci*9+dy*3+dx][co]
    __shared__ float red[4][8][2];
    const int t = threadIdx.x;
    // zero the x-pad columns
    for (int f = t; f < 8 * 34; f += 256) {
        const int ci = f / 34, yy = f % 34;
        li[ci][yy][0] = 0.f;
        li[ci][yy][31] = 0.f;
    }
    // load interior (and zero y-halo out of range)
    for (int f = t; f < 8 * 34 * 30; f += 256) {
        const int ci = f / (34 * 30);
        const int rem = f % (34 * 30);
        const int yy = rem / 30, xx = rem % 30;
        const int y = y0 - 1 + yy;
        float val = 0.f;
        if (y >= 0 && y < IMG_H)
            val = scores[(size_t)((rb * NHD + ci) * IMG_H + y) * NREF + xx];
        li[ci][yy][xx + 1] = val;
    }
    for (int f = t; f < 576; f += 256) {
        const int co = f / 72, r = f % 72;
        wl[r][co] = conv_w[f];             // conv_w[co*72 + r]
    }
    __syncthreads();
    float ls[8] = {0.f}, lss[8] = {0.f};
    for (int s = t; s < 32 * 30; s += 256) {
        const int yl = s / 30, xx = s % 30;
        float acc[8];
#pragma unroll
        for (int co = 0; co < 8; ++co) acc[co] = conv_b[co];
        for (int ci = 0; ci < 8; ++ci) {           // NOT unrolled
            const float* lp = &li[ci][yl][xx];     // tap (dy,dx) at lp[dy*32+dx]
            const float* wp = &wl[ci * 9][0];
#pragma unroll
            for (int dy = 0; dy < 3; ++dy) {
                const float a0 = lp[dy * 32 + 0];
                const float a1 = lp[dy * 32 + 1];
                const float a2 = lp[dy * 32 + 2];
                const float* w0 = wp + dy * 24;    // 3 dx rows of 8 co
#pragma unroll
                for (int co = 0; co < 8; ++co) {
                    float a = acc[co];
                    a = fmaf(a0, w0[co], a);
                    a = fmaf(a1, w0[8 + co], a);
                    a = fmaf(a2, w0[16 + co], a);
                    acc[co] = a;
                }
            }
        }
        const int y = y0 + yl;
#pragma unroll
        for (int co = 0; co < 8; ++co) {
            upd[(size_t)((rb * NHD + co) * IMG_H + y) * NREF + xx] = acc[co];
            ls[co] += acc[co];
            lss[co] += acc[co] * acc[co];
        }
    }
#pragma unroll
    for (int co = 0; co < 8; ++co) {
        float a = ls[co], b = lss[co];
        for (int off = 32; off; off >>= 1) {
            a += __shfl_down(a, off);
            b += __shfl_down(b, off);
        }
        if ((t & 63) == 0) { red[t >> 6][co][0] = a; red[t >> 6][co][1] = b; }
    }
    __syncthreads();
    if (t < 8) {
        const float a = red[0][t][0] + red[1][t][0] + red[2][t][0] + red[3][t][0];
        const float b = red[0][t][1] + red[1][t][1] + red[2][t][1] + red[3][t][1];
        atomicAdd(&stats[(rb * NHD + t) * 2], a);
        atomicAdd(&stats[(rb * NHD + t) * 2 + 1], b);
    }
}

// ---------------- LN + gelu + residual ----------------
__global__ __launch_bounds__(256) void k_apply(
    const float* __restrict__ upd, float* __restrict__ scores,
    const float* __restrict__ stats) {
    const int bid = blockIdx.x;            // 32*270
    const int img = bid / 270;
    const int off = (bid % 270) * 1024;
    const float s0 = stats[img * 2], s1 = stats[img * 2 + 1];
    const float mean = s0 * (1.f / LN_CNT);
    const float var = s1 * (1.f / LN_CNT) - mean * mean;
    const float rsig = rsqrtf(var + LN_EPS);
    const size_t base = (size_t)img * LN_CNT + off + threadIdx.x * 4;
    float4 u = *reinterpret_cast<const float4*>(&upd[base]);
    float4 sc = *reinterpret_cast<const float4*>(&scores[base]);
    sc.x += gelu_f((u.x - mean) * rsig);
    sc.y += gelu_f((u.y - mean) * rsig);
    sc.z += gelu_f((u.z - mean) * rsig);
    sc.w += gelu_f((u.w - mean) * rsig);
    *reinterpret_cast<float4*>(&scores[base]) = sc;
}

// ---------------- softmax over NREF + @ref_v * SCALE -> q_new ----------------
__global__ __launch_bounds__(64) void k_qnew(
    const float* __restrict__ scores, const float* __restrict__ ref_v,
    float* __restrict__ qbuf) {
    const int bid = blockIdx.x;            // ((rb*8+h)*144 + w)
    const int w = bid % NWIN;
    const int rh = bid / NWIN;
    const int h = rh % NHD, rb = rh / NHD;
    __shared__ float sl[64][NREF];
    __shared__ __align__(16) float rv[NREF][32];
    __shared__ __align__(16) float ob[64][32];
    const int t = threadIdx.x;
    const float* src = &scores[(size_t)((rb * NHD + h) * IMG_H + w * 64) * NREF];
    for (int u = t; u < 64 * NREF; u += 64) sl[u / NREF][u % NREF] = src[u];
    const float* rvs = &ref_v[(size_t)(rb * NHD + h) * NREF * HD];
    for (int u = t; u < NREF * 8; u += 64) {
        const int r = u >> 3, c4 = u & 7;
        *reinterpret_cast<float4*>(&rv[r][c4 * 4]) =
            *reinterpret_cast<const float4*>(&rvs[u * 4]);
    }
    __syncthreads();
    const int n = t;
    float p[NREF];
    float mx = -1e30f;
#pragma unroll
    for (int r = 0; r < NREF; ++r) { p[r] = sl[n][r]; mx = fmaxf(mx, p[r]); }
    float sum = 0.f;
#pragma unroll
    for (int r = 0; r < NREF; ++r) { p[r] = expf(p[r] - mx); sum += p[r]; }
    const float inv = SCALE / sum;
    float acc[32] = {0.f};
#pragma unroll
    for (int r = 0; r < NREF; ++r) {
        const float pr = p[r] * inv;
#pragma unroll
        for (int d = 0; d < 32; ++d) acc[d] += pr * rv[r][d];
    }
#pragma unroll
    for (int d = 0; d < 32; ++d) ob[n][d] = acc[d];
    __syncthreads();
    float* dst = &qbuf[(size_t)((rb * NWIN + w) * NHD + h) * NTOK * HD];
    for (int u = t; u < 512; u += 64)
        *reinterpret_cast<float4*>(&dst[u * 4]) =
            *reinterpret_cast<const float4*>(&ob[0][0] + u * 4);
}

// ---------------- window attention per (b,h) ----------------
__global__ __launch_bounds__(256) void k_wattn(
    const float* __restrict__ qbuf, const float* __restrict__ kbuf,
    const float* __restrict__ vbuf, const float* __restrict__ bias_table,
    const int* __restrict__ rel_index, const float* __restrict__ mask,
    float* __restrict__ pre) {
    const int bid = blockIdx.x;            // b*8 + h
    const int h = bid & 7;
    const int b = bid >> 3;
    const int w = b % NWIN;
    __shared__ __align__(16) float qs[64][36];
    __shared__ __align__(16) float ks[64][36];
    __shared__ __align__(16) float vs[64][36];
    __shared__ float S[64][66];
    const int t = threadIdx.x;
    const float* qsrc = &qbuf[(size_t)bid * 2048];
    const float* ksrc = &kbuf[(size_t)bid * 2048];
    const float* vsrc = &vbuf[(size_t)bid * 2048];
    for (int u = t; u < 512; u += 256) {
        const int row = u >> 3, c4 = u & 7;
        *reinterpret_cast<float4*>(&qs[row][c4 * 4]) = *reinterpret_cast<const float4*>(&qsrc[u * 4]);
        *reinterpret_cast<float4*>(&ks[row][c4 * 4]) = *reinterpret_cast<const float4*>(&ksrc[u * 4]);
        *reinterpret_cast<float4*>(&vs[row][c4 * 4]) = *reinterpret_cast<const float4*>(&vsrc[u * 4]);
    }
    __syncthreads();
    const int n = t >> 2, quad = t & 3;
    float q[32];
#pragma unroll
    for (int c4 = 0; c4 < 8; ++c4)
        *reinterpret_cast<float4*>(&q[c4 * 4]) = *reinterpret_cast<const float4*>(&qs[n][c4 * 4]);
    const int* ri = &rel_index[n * 64];
    const float* mrow = &mask[(size_t)(w * 64 + n) * 64];
    for (int mm = 0; mm < 16; ++mm) {
        const int m = quad * 16 + mm;
        float acc = 0.f;
#pragma unroll
        for (int d = 0; d < 32; ++d) acc += q[d] * ks[m][d];
        acc += bias_table[ri[m] * NHD + h] + mrow[m];
        S[n][m] = acc;
    }
    __syncthreads();
    float mx = -1e30f;
    for (int mm = 0; mm < 16; ++mm) mx = fmaxf(mx, S[n][quad * 16 + mm]);
    mx = fmaxf(mx, __shfl_xor(mx, 1));
    mx = fmaxf(mx, __shfl_xor(mx, 2));
    float sum = 0.f;
    for (int mm = 0; mm < 16; ++mm) {
        const float p = expf(S[n][quad * 16 + mm] - mx);
        S[n][quad * 16 + mm] = p;
        sum += p;
    }
    sum += __shfl_xor(sum, 1);
    sum += __shfl_xor(sum, 2);
    const float inv = 1.f / sum;
    __syncthreads();
    float acc[8] = {0.f};
    for (int m = 0; m < 64; ++m) {
        const float p = S[n][m];
#pragma unroll
        for (int d = 0; d < 8; ++d) acc[d] += p * vs[m][quad * 8 + d];
    }
    float* dst = &pre[(size_t)(b * 64 + n) * 256 + h * 32 + quad * 8];
#pragma unroll
    for (int d = 0; d < 8; ++d) dst[d] = acc[d] * inv;
}

extern "C" void kernel_launch(void* const* d_in, const int* in_sizes, int n_in,
                              void* d_out, int out_size, void* d_ws, size_t ws_size,
                              hipStream_t stream) {
    const float* x          = (const float*)d_in[0];
    const float* mask       = (const float*)d_in[1];
    const float* x_ref      = (const float*)d_in[2];
    const float* qkv_w      = (const float*)d_in[3];
    const float* qkv_b      = (const float*)d_in[4];
    const float* proj_w     = (const float*)d_in[5];
    const float* proj_b     = (const float*)d_in[6];
    const float* bias_table = (const float*)d_in[7];
    const float* diff_mu    = (const float*)d_in[8];
    const float* diff_ls    = (const float*)d_in[9];
    const float* ref_qk_w   = (const float*)d_in[10];
    const float* ref_qk_b   = (const float*)d_in[11];
    const float* conv_w     = (const float*)d_in[12];
    const float* conv_b     = (const float*)d_in[13];
    const int*   rel_index  = (const int*)d_in[14];
    float* out = (float*)d_out;
    float* ws = (float*)d_ws;

    float* qb  = ws;                       // 9437184
    float* kb  = qb + 9437184;             // 9437184
    float* vb  = kb + 9437184;             // 9437184
    float* sc  = vb + 9437184;             // 8847360
    float* up  = sc + 8847360;             // 8847360
    float* pre = sc;                       // alias: sc/up dead after k_qnew
    float* rq  = up + 8847360;             // 30720
    float* rv  = rq + 30720;               // 30720
    float* st  = rv + 30720;               // 64

    k_refprep<<<RB, 256, 0, stream>>>(x_ref, ref_qk_w, ref_qk_b, diff_mu, diff_ls, rq, rv);
    dim3 g1(576, 12);
    k_qkv<<<g1, 256, 0, stream>>>(x, qkv_w, qkv_b, qb, kb, vb);
    k_scores<<<RB * NHD * NWIN, 64, 0, stream>>>(qb, rq, sc);
    for (int it = 0; it < 3; ++it) {
        hipMemsetAsync(st, 0, 64 * sizeof(float), stream);
        k_conv<<<RB * 288, 256, 0, stream>>>(sc, conv_w, conv_b, up, st);
        k_apply<<<32 * 270, 256, 0, stream>>>(up, sc, st);
    }
    k_qnew<<<RB * NHD * NWIN, 64, 0, stream>>>(sc, rv, qb);
    k_wattn<<<576 * NHD, 256, 0, stream>>>(qb, kb, vb, bias_table, rel_index, mask, pre);
    dim3 g2(576, 4);
    k_proj<<<g2, 256, 0, stream>>>(pre, proj_w, proj_b, out);
}

// Round 3
// 813.585 us; speedup vs baseline: 2.1602x; 1.2173x over previous
//
#include <hip/hip_runtime.h>
#include <math.h>

#define NHD 8
#define HD 32
#define NREF 30
#define RB 4
#define NWIN 144
#define NTOK 64
#define IMG_H (NWIN*NTOK)        /* 9216  */
#define LN_CNT (IMG_H*NREF)      /* 276480 */
#define SCALE 0.1767766952966369f
#define LN_EPS 1e-5f

typedef __attribute__((ext_vector_type(8))) short bf8_t;   // 8 x bf16
typedef __attribute__((ext_vector_type(4))) float f4_t;    // MFMA acc

__device__ __forceinline__ float gelu_f(float v) {
    return 0.5f * v * (1.0f + erff(v * 0.7071067811865476f));
}

__device__ __forceinline__ short f2bf(float f) {           // fp32 -> bf16 RNE
    union { float f; unsigned u; } v; v.f = f;
    unsigned r = v.u + 0x7fffu + ((v.u >> 16) & 1u);
    return (short)(r >> 16);
}

// ---------------- ref_q / ref_v prep (tiny) ----------------
__global__ __launch_bounds__(256) void k_refprep(
    const float* __restrict__ x_ref, const float* __restrict__ rw,
    const float* __restrict__ rbias, const float* __restrict__ dmu,
    const float* __restrict__ dls, float* __restrict__ ref_q,
    float* __restrict__ ref_v) {
    __shared__ float Wl[60][NREF];
    __shared__ float Bl[60];
    const int rb = blockIdx.x;
    const int t = threadIdx.x;
    for (int i = t; i < 60 * NREF; i += 256) Wl[i / NREF][i % NREF] = rw[i];
    if (t < 60) Bl[t] = rbias[t];
    __syncthreads();
    const int d = t;                       // 0..255
    float xr[NREF];
#pragma unroll
    for (int r = 0; r < NREF; ++r) xr[r] = x_ref[(rb * 256 + d) * NREF + r];
    const int h = d >> 5, hd = d & 31;
    const float mu = dmu[d], sg = expf(dls[d]);
    for (int j = 0; j < 60; ++j) {
        float acc = Bl[j];
#pragma unroll
        for (int r = 0; r < NREF; ++r) acc += xr[r] * Wl[j][r];
        if (j < NREF)
            ref_q[((rb * NHD + h) * NREF + j) * HD + hd] = mu + sg * acc;
        else
            ref_v[((rb * NHD + h) * NREF + (j - NREF)) * HD + hd] = acc;
    }
}

// ---------------- qkv GEMM via bf16 MFMA: (36864x256)@(256x768)^T + scatter ----
// 64x64 tile, K=256 staged once (A 32KB + B 32KB LDS, bf16, XOR-swizzled rows).
// 4 waves, each 32x32 (2x2 frags of 16x16x32). XCD-bijective block swizzle.
__global__ __launch_bounds__(256) void k_qkv_mfma(
    const float* __restrict__ x, const float* __restrict__ w,
    const float* __restrict__ bias, float* __restrict__ qb,
    float* __restrict__ kb, float* __restrict__ vb) {
    __shared__ __align__(16) char As[64 * 512];
    __shared__ __align__(16) char Bs[64 * 512];
    const int t = threadIdx.x;
    const int bid = blockIdx.x;
    const int swz = (bid & 7) * (6912 / 8) + (bid >> 3);
    const int r0 = (swz / 12) * 64;
    const int c0 = (swz % 12) * 64;
#pragma unroll
    for (int i = 0; i < 8; ++i) {
        const int c = t + 256 * i;
        const int row = c >> 5, k8 = c & 31;
        const float* sa = &x[(size_t)(r0 + row) * 256 + k8 * 8];
        float4 a0 = *reinterpret_cast<const float4*>(sa);
        float4 a1 = *reinterpret_cast<const float4*>(sa + 4);
        bf8_t pa;
        pa[0] = f2bf(a0.x); pa[1] = f2bf(a0.y); pa[2] = f2bf(a0.z); pa[3] = f2bf(a0.w);
        pa[4] = f2bf(a1.x); pa[5] = f2bf(a1.y); pa[6] = f2bf(a1.z); pa[7] = f2bf(a1.w);
        *reinterpret_cast<bf8_t*>(As + row * 512 + ((k8 * 16) ^ ((row & 7) << 4))) = pa;
        const float* sb = &w[(size_t)(c0 + row) * 256 + k8 * 8];
        float4 b0 = *reinterpret_cast<const float4*>(sb);
        float4 b1 = *reinterpret_cast<const float4*>(sb + 4);
        bf8_t pb;
        pb[0] = f2bf(b0.x); pb[1] = f2bf(b0.y); pb[2] = f2bf(b0.z); pb[3] = f2bf(b0.w);
        pb[4] = f2bf(b1.x); pb[5] = f2bf(b1.y); pb[6] = f2bf(b1.z); pb[7] = f2bf(b1.w);
        *reinterpret_cast<bf8_t*>(Bs + row * 512 + ((k8 * 16) ^ ((row & 7) << 4))) = pb;
    }
    __syncthreads();
    const int wid = t >> 6, l = t & 63;
    const int wr = wid >> 1, wc = wid & 1;
    const int lr = l & 15, lg = l >> 4;
    const int sw = (lr & 7) << 4;
    const char* Ap0 = As + (wr * 32 + lr) * 512;
    const char* Ap1 = As + (wr * 32 + 16 + lr) * 512;
    const char* Bp0 = Bs + (wc * 32 + lr) * 512;
    const char* Bp1 = Bs + (wc * 32 + 16 + lr) * 512;
    f4_t acc[2][2] = {};
#pragma unroll
    for (int kk = 0; kk < 8; ++kk) {
        const int ka = (kk * 64 + lg * 16) ^ sw;
        bf8_t a0 = *reinterpret_cast<const bf8_t*>(Ap0 + ka);
        bf8_t a1 = *reinterpret_cast<const bf8_t*>(Ap1 + ka);
        bf8_t b0 = *reinterpret_cast<const bf8_t*>(Bp0 + ka);
        bf8_t b1 = *reinterpret_cast<const bf8_t*>(Bp1 + ka);
        acc[0][0] = __builtin_amdgcn_mfma_f32_16x16x32_bf16(a0, b0, acc[0][0], 0, 0, 0);
        acc[0][1] = __builtin_amdgcn_mfma_f32_16x16x32_bf16(a0, b1, acc[0][1], 0, 0, 0);
        acc[1][0] = __builtin_amdgcn_mfma_f32_16x16x32_bf16(a1, b0, acc[1][0], 0, 0, 0);
        acc[1][1] = __builtin_amdgcn_mfma_f32_16x16x32_bf16(a1, b1, acc[1][1], 0, 0, 0);
    }
#pragma unroll
    for (int ni = 0; ni < 2; ++ni) {
        const int gc = c0 + wc * 32 + ni * 16 + lr;
        const int i3 = gc >> 8, rem = gc & 255;
        const int h = rem >> 5, hd = rem & 31;
        float* dst = (i3 == 0) ? qb : (i3 == 1) ? kb : vb;
        const float bv = bias[gc];
#pragma unroll
        for (int mi = 0; mi < 2; ++mi) {
#pragma unroll
            for (int j = 0; j < 4; ++j) {
                const int gr = r0 + wr * 32 + mi * 16 + lg * 4 + j;
                const int bb = gr >> 6, n = gr & 63;
                dst[(size_t)((bb * NHD + h) * NTOK + n) * HD + hd] = acc[mi][ni][j] + bv;
            }
        }
    }
}

// ---------------- proj GEMM via bf16 MFMA: (36864x256)@(256x256)^T ------------
__global__ __launch_bounds__(256) void k_proj_mfma(
    const float* __restrict__ A, const float* __restrict__ w,
    const float* __restrict__ bias, float* __restrict__ out) {
    __shared__ __align__(16) char As[64 * 512];
    __shared__ __align__(16) char Bs[64 * 512];
    const int t = threadIdx.x;
    const int bid = blockIdx.x;
    const int swz = (bid & 7) * (2304 / 8) + (bid >> 3);
    const int r0 = (swz / 4) * 64;
    const int c0 = (swz % 4) * 64;
#pragma unroll
    for (int i = 0; i < 8; ++i) {
        const int c = t + 256 * i;
        const int row = c >> 5, k8 = c & 31;
        const float* sa = &A[(size_t)(r0 + row) * 256 + k8 * 8];
        float4 a0 = *reinterpret_cast<const float4*>(sa);
        float4 a1 = *reinterpret_cast<const float4*>(sa + 4);
        bf8_t pa;
        pa[0] = f2bf(a0.x); pa[1] = f2bf(a0.y); pa[2] = f2bf(a0.z); pa[3] = f2bf(a0.w);
        pa[4] = f2bf(a1.x); pa[5] = f2bf(a1.y); pa[6] = f2bf(a1.z); pa[7] = f2bf(a1.w);
        *reinterpret_cast<bf8_t*>(As + row * 512 + ((k8 * 16) ^ ((row & 7) << 4))) = pa;
        const float* sb = &w[(size_t)(c0 + row) * 256 + k8 * 8];
        float4 b0 = *reinterpret_cast<const float4*>(sb);
        float4 b1 = *reinterpret_cast<const float4*>(sb + 4);
        bf8_t pb;
        pb[0] = f2bf(b0.x); pb[1] = f2bf(b0.y); pb[2] = f2bf(b0.z); pb[3] = f2bf(b0.w);
        pb[4] = f2bf(b1.x); pb[5] = f2bf(b1.y); pb[6] = f2bf(b1.z); pb[7] = f2bf(b1.w);
        *reinterpret_cast<bf8_t*>(Bs + row * 512 + ((k8 * 16) ^ ((row & 7) << 4))) = pb;
    }
    __syncthreads();
    const int wid = t >> 6, l = t & 63;
    const int wr = wid >> 1, wc = wid & 1;
    const int lr = l & 15, lg = l >> 4;
    const int sw = (lr & 7) << 4;
    const char* Ap0 = As + (wr * 32 + lr) * 512;
    const char* Ap1 = As + (wr * 32 + 16 + lr) * 512;
    const char* Bp0 = Bs + (wc * 32 + lr) * 512;
    const char* Bp1 = Bs + (wc * 32 + 16 + lr) * 512;
    f4_t acc[2][2] = {};
#pragma unroll
    for (int kk = 0; kk < 8; ++kk) {
        const int ka = (kk * 64 + lg * 16) ^ sw;
        bf8_t a0 = *reinterpret_cast<const bf8_t*>(Ap0 + ka);
        bf8_t a1 = *reinterpret_cast<const bf8_t*>(Ap1 + ka);
        bf8_t b0 = *reinterpret_cast<const bf8_t*>(Bp0 + ka);
        bf8_t b1 = *reinterpret_cast<const bf8_t*>(Bp1 + ka);
        acc[0][0] = __builtin_amdgcn_mfma_f32_16x16x32_bf16(a0, b0, acc[0][0], 0, 0, 0);
        acc[0][1] = __builtin_amdgcn_mfma_f32_16x16x32_bf16(a0, b1, acc[0][1], 0, 0, 0);
        acc[1][0] = __builtin_amdgcn_mfma_f32_16x16x32_bf16(a1, b0, acc[1][0], 0, 0, 0);
        acc[1][1] = __builtin_amdgcn_mfma_f32_16x16x32_bf16(a1, b1, acc[1][1], 0, 0, 0);
    }
#pragma unroll
    for (int ni = 0; ni < 2; ++ni) {
        const int gc = c0 + wc * 32 + ni * 16 + lr;
        const float bv = bias[gc];
#pragma unroll
        for (int mi = 0; mi < 2; ++mi) {
#pragma unroll
            for (int j = 0; j < 4; ++j) {
                const int gr = r0 + wr * 32 + mi * 16 + lg * 4 + j;
                out[(size_t)gr * 256 + gc] = acc[mi][ni][j] + bv;
            }
        }
    }
}

// ---------------- ref scores: q . ref_q -> (rb,h, y=w*64+n, r) ----------------
__global__ __launch_bounds__(64) void k_scores(
    const float* __restrict__ qbuf, const float* __restrict__ ref_q,
    float* __restrict__ scores) {
    const int bid = blockIdx.x;            // ((rb*8+h)*144 + w)
    const int w = bid % NWIN;
    const int rh = bid / NWIN;
    const int h = rh % NHD, rb = rh / NHD;
    __shared__ __align__(16) float qs[64][36];
    __shared__ __align__(16) float rs[NREF][32];
    __shared__ float outb[64 * NREF];
    const int t = threadIdx.x;
    const float* qsrc = &qbuf[(size_t)((rb * NWIN + w) * NHD + h) * NTOK * HD];
    for (int u = t; u < 512; u += 64) {
        const int row = u >> 3, c4 = u & 7;
        *reinterpret_cast<float4*>(&qs[row][c4 * 4]) =
            *reinterpret_cast<const float4*>(&qsrc[u * 4]);
    }
    const float* rsrc = &ref_q[(size_t)(rb * NHD + h) * NREF * HD];
    for (int u = t; u < NREF * 8; u += 64) {
        const int row = u >> 3, c4 = u & 7;
        *reinterpret_cast<float4*>(&rs[row][c4 * 4]) =
            *reinterpret_cast<const float4*>(&rsrc[u * 4]);
    }
    __syncthreads();
    const int n = t;
    float q[32];
#pragma unroll
    for (int c4 = 0; c4 < 8; ++c4)
        *reinterpret_cast<float4*>(&q[c4 * 4]) = *reinterpret_cast<const float4*>(&qs[n][c4 * 4]);
    for (int r = 0; r < NREF; ++r) {
        float acc = 0.f;
#pragma unroll
        for (int d = 0; d < 32; ++d) acc += q[d] * rs[r][d];
        outb[n * NREF + r] = acc;
    }
    __syncthreads();
    float* dst = &scores[(size_t)((rb * NHD + h) * IMG_H + w * 64) * NREF];
    for (int u = t; u < 64 * NREF; u += 64) dst[u] = outb[u];
}

// ---------------- conv 3x3 (NCHW 4,8,9216,30) + sum/sumsq stats ----------------
__global__ __launch_bounds__(256) void k_conv(
    const float* __restrict__ scores, const float* __restrict__ conv_w,
    const float* __restrict__ conv_b, float* __restrict__ upd,
    float* __restrict__ stats) {
    const int bid = blockIdx.x;            // rb*288 + ychunk
    const int rb = bid / 288;
    const int y0 = (bid % 288) * 32;
    __shared__ float li[8][34][32];        // [ci][yy][x+1], x-padded
    __shared__ float wl[72][8];            // [ci*9+dy*3+dx][co]
    __shared__ float red[4][8][2];
    const int t = threadIdx.x;
    for (int f = t; f < 8 * 34; f += 256) {
        const int ci = f / 34, yy = f % 34;
        li[ci][yy][0] = 0.f;
        li[ci][yy][31] = 0.f;
    }
    for (int f = t; f < 8 * 34 * 30; f += 256) {
        const int ci = f / (34 * 30);
        const int rem = f % (34 * 30);
        const int yy = rem / 30, xx = rem % 30;
        const int y = y0 - 1 + yy;
        float val = 0.f;
        if (y >= 0 && y < IMG_H)
            val = scores[(size_t)((rb * NHD + ci) * IMG_H + y) * NREF + xx];
        li[ci][yy][xx + 1] = val;
    }
    for (int f = t; f < 576; f += 256) {
        const int co = f / 72, r = f % 72;
        wl[r][co] = conv_w[f];             // conv_w[co*72 + r]
    }
    __syncthreads();
    float ls[8] = {0.f}, lss[8] = {0.f};
    for (int s = t; s < 32 * 30; s += 256) {
        const int yl = s / 30, xx = s % 30;
        float acc[8];
#pragma unroll
        for (int co = 0; co < 8; ++co) acc[co] = conv_b[co];
        for (int ci = 0; ci < 8; ++ci) {           // NOT unrolled
            const float* lp = &li[ci][yl][xx];     // tap (dy,dx) at lp[dy*32+dx]
            const float* wp = &wl[ci * 9][0];
#pragma unroll
            for (int dy = 0; dy < 3; ++dy) {
                const float a0 = lp[dy * 32 + 0];
                const float a1 = lp[dy * 32 + 1];
                const float a2 = lp[dy * 32 + 2];
                const float* w0 = wp + dy * 24;    // 3 dx rows of 8 co
#pragma unroll
                for (int co = 0; co < 8; ++co) {
                    float a = acc[co];
                    a = fmaf(a0, w0[co], a);
                    a = fmaf(a1, w0[8 + co], a);
                    a = fmaf(a2, w0[16 + co], a);
                    acc[co] = a;
                }
            }
        }
        const int y = y0 + yl;
#pragma unroll
        for (int co = 0; co < 8; ++co) {
            upd[(size_t)((rb * NHD + co) * IMG_H + y) * NREF + xx] = acc[co];
            ls[co] += acc[co];
            lss[co] += acc[co] * acc[co];
        }
    }
#pragma unroll
    for (int co = 0; co < 8; ++co) {
        float a = ls[co], b = lss[co];
        for (int off = 32; off; off >>= 1) {
            a += __shfl_down(a, off);
            b += __shfl_down(b, off);
        }
        if ((t & 63) == 0) { red[t >> 6][co][0] = a; red[t >> 6][co][1] = b; }
    }
    __syncthreads();
    if (t < 8) {
        const float a = red[0][t][0] + red[1][t][0] + red[2][t][0] + red[3][t][0];
        const float b = red[0][t][1] + red[1][t][1] + red[2][t][1] + red[3][t][1];
        atomicAdd(&stats[(rb * NHD + t) * 2], a);
        atomicAdd(&stats[(rb * NHD + t) * 2 + 1], b);
    }
}

// ---------------- LN + gelu + residual ----------------
__global__ __launch_bounds__(256) void k_apply(
    const float* __restrict__ upd, float* __restrict__ scores,
    const float* __restrict__ stats) {
    const int bid = blockIdx.x;            // 32*270
    const int img = bid / 270;
    const int off = (bid % 270) * 1024;
    const float s0 = stats[img * 2], s1 = stats[img * 2 + 1];
    const float mean = s0 * (1.f / LN_CNT);
    const float var = s1 * (1.f / LN_CNT) - mean * mean;
    const float rsig = rsqrtf(var + LN_EPS);
    const size_t base = (size_t)img * LN_CNT + off + threadIdx.x * 4;
    float4 u = *reinterpret_cast<const float4*>(&upd[base]);
    float4 sc = *reinterpret_cast<const float4*>(&scores[base]);
    sc.x += gelu_f((u.x - mean) * rsig);
    sc.y += gelu_f((u.y - mean) * rsig);
    sc.z += gelu_f((u.z - mean) * rsig);
    sc.w += gelu_f((u.w - mean) * rsig);
    *reinterpret_cast<float4*>(&scores[base]) = sc;
}

// ---------------- softmax over NREF + @ref_v * SCALE -> q_new ----------------
__global__ __launch_bounds__(64) void k_qnew(
    const float* __restrict__ scores, const float* __restrict__ ref_v,
    float* __restrict__ qbuf) {
    const int bid = blockIdx.x;            // ((rb*8+h)*144 + w)
    const int w = bid % NWIN;
    const int rh = bid / NWIN;
    const int h = rh % NHD, rb = rh / NHD;
    __shared__ float sl[64][NREF];
    __shared__ __align__(16) float rv[NREF][32];
    __shared__ __align__(16) float ob[64][32];
    const int t = threadIdx.x;
    const float* src = &scores[(size_t)((rb * NHD + h) * IMG_H + w * 64) * NREF];
    for (int u = t; u < 64 * NREF; u += 64) sl[u / NREF][u % NREF] = src[u];
    const float* rvs = &ref_v[(size_t)(rb * NHD + h) * NREF * HD];
    for (int u = t; u < NREF * 8; u += 64) {
        const int r = u >> 3, c4 = u & 7;
        *reinterpret_cast<float4*>(&rv[r][c4 * 4]) =
            *reinterpret_cast<const float4*>(&rvs[u * 4]);
    }
    __syncthreads();
    const int n = t;
    float p[NREF];
    float mx = -1e30f;
#pragma unroll
    for (int r = 0; r < NREF; ++r) { p[r] = sl[n][r]; mx = fmaxf(mx, p[r]); }
    float sum = 0.f;
#pragma unroll
    for (int r = 0; r < NREF; ++r) { p[r] = expf(p[r] - mx); sum += p[r]; }
    const float inv = SCALE / sum;
    float acc[32] = {0.f};
#pragma unroll
    for (int r = 0; r < NREF; ++r) {
        const float pr = p[r] * inv;
#pragma unroll
        for (int d = 0; d < 32; ++d) acc[d] += pr * rv[r][d];
    }
#pragma unroll
    for (int d = 0; d < 32; ++d) ob[n][d] = acc[d];
    __syncthreads();
    float* dst = &qbuf[(size_t)((rb * NWIN + w) * NHD + h) * NTOK * HD];
    for (int u = t; u < 512; u += 64)
        *reinterpret_cast<float4*>(&dst[u * 4]) =
            *reinterpret_cast<const float4*>(&ob[0][0] + u * 4);
}

// ---------------- window attention per (b,h) ----------------
__global__ __launch_bounds__(256) void k_wattn(
    const float* __restrict__ qbuf, const float* __restrict__ kbuf,
    const float* __restrict__ vbuf, const float* __restrict__ bias_table,
    const int* __restrict__ rel_index, const float* __restrict__ mask,
    float* __restrict__ pre) {
    const int bid = blockIdx.x;            // b*8 + h
    const int h = bid & 7;
    const int b = bid >> 3;
    const int w = b % NWIN;
    __shared__ __align__(16) float qs[64][36];
    __shared__ __align__(16) float ks[64][36];
    __shared__ __align__(16) float vs[64][36];
    __shared__ float S[64][66];
    const int t = threadIdx.x;
    const float* qsrc = &qbuf[(size_t)bid * 2048];
    const float* ksrc = &kbuf[(size_t)bid * 2048];
    const float* vsrc = &vbuf[(size_t)bid * 2048];
    for (int u = t; u < 512; u += 256) {
        const int row = u >> 3, c4 = u & 7;
        *reinterpret_cast<float4*>(&qs[row][c4 * 4]) = *reinterpret_cast<const float4*>(&qsrc[u * 4]);
        *reinterpret_cast<float4*>(&ks[row][c4 * 4]) = *reinterpret_cast<const float4*>(&ksrc[u * 4]);
        *reinterpret_cast<float4*>(&vs[row][c4 * 4]) = *reinterpret_cast<const float4*>(&vsrc[u * 4]);
    }
    __syncthreads();
    const int n = t >> 2, quad = t & 3;
    float q[32];
#pragma unroll
    for (int c4 = 0; c4 < 8; ++c4)
        *reinterpret_cast<float4*>(&q[c4 * 4]) = *reinterpret_cast<const float4*>(&qs[n][c4 * 4]);
    const int* ri = &rel_index[n * 64];
    const float* mrow = &mask[(size_t)(w * 64 + n) * 64];
    for (int mm = 0; mm < 16; ++mm) {
        const int m = quad * 16 + mm;
        float acc = 0.f;
#pragma unroll
        for (int d = 0; d < 32; ++d) acc += q[d] * ks[m][d];
        acc += bias_table[ri[m] * NHD + h] + mrow[m];
        S[n][m] = acc;
    }
    __syncthreads();
    float mx = -1e30f;
    for (int mm = 0; mm < 16; ++mm) mx = fmaxf(mx, S[n][quad * 16 + mm]);
    mx = fmaxf(mx, __shfl_xor(mx, 1));
    mx = fmaxf(mx, __shfl_xor(mx, 2));
    float sum = 0.f;
    for (int mm = 0; mm < 16; ++mm) {
        const float p = expf(S[n][quad * 16 + mm] - mx);
        S[n][quad * 16 + mm] = p;
        sum += p;
    }
    sum += __shfl_xor(sum, 1);
    sum += __shfl_xor(sum, 2);
    const float inv = 1.f / sum;
    __syncthreads();
    float acc[8] = {0.f};
    for (int m = 0; m < 64; ++m) {
        const float p = S[n][m];
#pragma unroll
        for (int d = 0; d < 8; ++d) acc[d] += p * vs[m][quad * 8 + d];
    }
    float* dst = &pre[(size_t)(b * 64 + n) * 256 + h * 32 + quad * 8];
#pragma unroll
    for (int d = 0; d < 8; ++d) dst[d] = acc[d] * inv;
}

extern "C" void kernel_launch(void* const* d_in, const int* in_sizes, int n_in,
                              void* d_out, int out_size, void* d_ws, size_t ws_size,
                              hipStream_t stream) {
    const float* x          = (const float*)d_in[0];
    const float* mask       = (const float*)d_in[1];
    const float* x_ref      = (const float*)d_in[2];
    const float* qkv_w      = (const float*)d_in[3];
    const float* qkv_b      = (const float*)d_in[4];
    const float* proj_w     = (const float*)d_in[5];
    const float* proj_b     = (const float*)d_in[6];
    const float* bias_table = (const float*)d_in[7];
    const float* diff_mu    = (const float*)d_in[8];
    const float* diff_ls    = (const float*)d_in[9];
    const float* ref_qk_w   = (const float*)d_in[10];
    const float* ref_qk_b   = (const float*)d_in[11];
    const float* conv_w     = (const float*)d_in[12];
    const float* conv_b     = (const float*)d_in[13];
    const int*   rel_index  = (const int*)d_in[14];
    float* out = (float*)d_out;
    float* ws = (float*)d_ws;

    float* qb  = ws;                       // 9437184
    float* kb  = qb + 9437184;             // 9437184
    float* vb  = kb + 9437184;             // 9437184
    float* sc  = vb + 9437184;             // 8847360
    float* up  = sc + 8847360;             // 8847360
    float* pre = sc;                       // alias: sc/up dead after k_qnew
    float* rq  = up + 8847360;             // 30720
    float* rv  = rq + 30720;               // 30720
    float* st  = rv + 30720;               // 64

    k_refprep<<<RB, 256, 0, stream>>>(x_ref, ref_qk_w, ref_qk_b, diff_mu, diff_ls, rq, rv);
    k_qkv_mfma<<<6912, 256, 0, stream>>>(x, qkv_w, qkv_b, qb, kb, vb);
    k_scores<<<RB * NHD * NWIN, 64, 0, stream>>>(qb, rq, sc);
    for (int it = 0; it < 3; ++it) {
        hipMemsetAsync(st, 0, 64 * sizeof(float), stream);
        k_conv<<<RB * 288, 256, 0, stream>>>(sc, conv_w, conv_b, up, st);
        k_apply<<<32 * 270, 256, 0, stream>>>(up, sc, st);
    }
    k_qnew<<<RB * NHD * NWIN, 64, 0, stream>>>(sc, rv, qb);
    k_wattn<<<576 * NHD, 256, 0, stream>>>(qb, kb, vb, bias_table, rel_index, mask, pre);
    k_proj_mfma<<<2304, 256, 0, stream>>>(pre, proj_w, proj_b, out);
}